// Round 3
// baseline (1383.357 us; speedup 1.0000x reference)
//
#include <hip/hip_runtime.h>

// Problem: B=2, H=16, S=2048, D=128
//   k_t = k.reshape(b,h,d,s)          -> B-operand is k slice with ldb=S
//   score_pre = q @ k_t / sqrt(D)     -> [B,H,S,S]
//   score = softmax over HEAD axis (axis=1) of where(mask==0, -1e-12, score_pre)
//           (mask identical across heads -> masked positions = exactly 1/16)
//   out = score @ v                   -> [B,H,S,D]
//   returns (out, score): d_out = [out (8388608 f32)][score (134217728 f32)]

#define SS 2048
#define DD 128
#define HH 16
#define BB 2

typedef short bf16x8 __attribute__((ext_vector_type(8)));
typedef float f32x4 __attribute__((ext_vector_type(4)));

__device__ __forceinline__ unsigned short f2bf(float f) {
  union { float f; unsigned u; } x; x.f = f;
  unsigned u = x.u;
  unsigned r = u + 0x7fffu + ((u >> 16) & 1u);   // RN-even to bf16
  return (unsigned short)(r >> 16);
}

// Batched C[M,N] = scale * A[M,K] @ B[K,N], batch = blockIdx.z.
// BM=BN=128, BK=64; 256 threads = 4 waves (2x2), each wave computes 64x64
// via 4x4 fragments of v_mfma_f32_16x16x32_bf16.
// A fragment layout: row = lane&15, k = (lane>>4)*8 + e
// B fragment layout: col = lane&15, k = (lane>>4)*8 + e
// D fragment layout: col = lane&15, row = (lane>>4)*4 + reg   [m89-verified]
__global__ __launch_bounds__(256)
void gemm_bf16(const float* __restrict__ Ag, const float* __restrict__ Bg,
               float* __restrict__ Cg, int Kdim,
               long lda, long ldb, long ldc,
               long sA, long sB, long sC, float scale)
{
  constexpr int BM = 128, BN = 128, BK = 64, LDSK = BK + 8;  // pad: 72 bf16 = 144 B row stride
  const float* A = Ag + (long)blockIdx.z * sA;
  const float* B = Bg + (long)blockIdx.z * sB;
  float*       C = Cg + (long)blockIdx.z * sC;
  const int i0 = blockIdx.x * BM;
  const int j0 = blockIdx.y * BN;
  const int tid  = threadIdx.x;
  const int lane = tid & 63;
  const int wv   = tid >> 6;
  const int wr   = (wv >> 1) * 64;   // wave row offset in tile
  const int wc   = (wv & 1) * 64;    // wave col offset in tile
  const int l15  = lane & 15;
  const int lhi  = lane >> 4;        // 0..3

  __shared__ unsigned short As[BM][LDSK];   // [row][k], bf16
  __shared__ unsigned short Bt[BN][LDSK];   // [col][k], bf16 (transposed)

  f32x4 acc[4][4];
  #pragma unroll
  for (int a = 0; a < 4; ++a)
    #pragma unroll
    for (int b = 0; b < 4; ++b)
      acc[a][b] = (f32x4){0.f, 0.f, 0.f, 0.f};

  for (int k0 = 0; k0 < Kdim; k0 += BK) {
    // ---- stage A: BM x BK fp32 -> bf16 LDS (coalesced float4 loads) ----
    #pragma unroll
    for (int it = 0; it < 8; ++it) {
      const int lin = tid + it * 256;           // 0..2047
      const int row = lin >> 4;                 // BK/4 = 16 float4 per row
      const int c4  = lin & 15;
      const float4 v = *reinterpret_cast<const float4*>(
          A + (long)(i0 + row) * lda + (k0 + c4 * 4));
      ushort4 sv;
      sv.x = f2bf(v.x); sv.y = f2bf(v.y); sv.z = f2bf(v.z); sv.w = f2bf(v.w);
      *reinterpret_cast<ushort4*>(&As[row][c4 * 4]) = sv;
    }
    // ---- stage B transposed: BK x BN fp32 -> Bt[col][k] ----
    #pragma unroll
    for (int it = 0; it < 8; ++it) {
      const int lin = tid + it * 256;           // 0..2047
      const int kr  = lin >> 5;                 // BN/4 = 32 float4 per row
      const int j4  = lin & 31;
      const float4 v = *reinterpret_cast<const float4*>(
          B + (long)(k0 + kr) * ldb + (j0 + j4 * 4));
      Bt[j4 * 4 + 0][kr] = f2bf(v.x);
      Bt[j4 * 4 + 1][kr] = f2bf(v.y);
      Bt[j4 * 4 + 2][kr] = f2bf(v.z);
      Bt[j4 * 4 + 3][kr] = f2bf(v.w);
    }
    __syncthreads();
    // ---- MFMA inner: 2 k-steps of 32 ----
    #pragma unroll
    for (int kk = 0; kk < 2; ++kk) {
      const int kcol = kk * 32 + lhi * 8;
      bf16x8 afr[4], bfr[4];
      #pragma unroll
      for (int mi = 0; mi < 4; ++mi)
        afr[mi] = *reinterpret_cast<const bf16x8*>(&As[wr + mi * 16 + l15][kcol]);
      #pragma unroll
      for (int ni = 0; ni < 4; ++ni)
        bfr[ni] = *reinterpret_cast<const bf16x8*>(&Bt[wc + ni * 16 + l15][kcol]);
      #pragma unroll
      for (int mi = 0; mi < 4; ++mi)
        #pragma unroll
        for (int ni = 0; ni < 4; ++ni)
          acc[mi][ni] = __builtin_amdgcn_mfma_f32_16x16x32_bf16(
              afr[mi], bfr[ni], acc[mi][ni], 0, 0, 0);
    }
    __syncthreads();
  }

  // ---- epilogue: D layout col=lane&15, row=(lane>>4)*4+r ----
  #pragma unroll
  for (int mi = 0; mi < 4; ++mi) {
    #pragma unroll
    for (int ni = 0; ni < 4; ++ni) {
      const int col = j0 + wc + ni * 16 + l15;
      #pragma unroll
      for (int r = 0; r < 4; ++r) {
        const int row = i0 + wr + mi * 16 + lhi * 4 + r;
        C[(long)row * ldc + col] = acc[mi][ni][r] * scale;
      }
    }
  }
}

// In-place softmax over the HEAD axis (16 planes at stride S*S), with
// masked_fill replicated via mask==0 -> 0 for all heads (softmax of equal
// values == 1/16 exactly, matching reference's -1e-12 for all heads).
__global__ __launch_bounds__(256)
void softmax_heads(float* __restrict__ sc, const int* __restrict__ mask)
{
  const unsigned gid = blockIdx.x * 256u + threadIdx.x;  // 0..2^21-1
  const int j4 = gid & 511;              // S/4 = 512 groups per row
  const int i  = (gid >> 9) & 2047;
  const int b  = gid >> 20;              // 0..1
  const long PL = (long)SS * SS;
  const long off = (long)b * HH * PL + (long)i * SS + j4 * 4;

  const int4 mk = *reinterpret_cast<const int4*>(mask + (long)i * SS + j4 * 4);

  float4 s[16];
  #pragma unroll
  for (int h = 0; h < HH; ++h) {
    float4 v = *reinterpret_cast<const float4*>(sc + off + (long)h * PL);
    v.x = mk.x ? v.x : 0.0f;
    v.y = mk.y ? v.y : 0.0f;
    v.z = mk.z ? v.z : 0.0f;
    v.w = mk.w ? v.w : 0.0f;
    s[h] = v;
  }
  float4 mx = s[0];
  #pragma unroll
  for (int h = 1; h < HH; ++h) {
    mx.x = fmaxf(mx.x, s[h].x);
    mx.y = fmaxf(mx.y, s[h].y);
    mx.z = fmaxf(mx.z, s[h].z);
    mx.w = fmaxf(mx.w, s[h].w);
  }
  float4 sum = {0.f, 0.f, 0.f, 0.f};
  #pragma unroll
  for (int h = 0; h < HH; ++h) {
    s[h].x = __expf(s[h].x - mx.x);
    s[h].y = __expf(s[h].y - mx.y);
    s[h].z = __expf(s[h].z - mx.z);
    s[h].w = __expf(s[h].w - mx.w);
    sum.x += s[h].x; sum.y += s[h].y; sum.z += s[h].z; sum.w += s[h].w;
  }
  const float4 inv = {1.0f / sum.x, 1.0f / sum.y, 1.0f / sum.z, 1.0f / sum.w};
  #pragma unroll
  for (int h = 0; h < HH; ++h) {
    float4 o;
    o.x = s[h].x * inv.x; o.y = s[h].y * inv.y;
    o.z = s[h].z * inv.z; o.w = s[h].w * inv.w;
    *reinterpret_cast<float4*>(sc + off + (long)h * PL) = o;
  }
}

extern "C" void kernel_launch(void* const* d_in, const int* in_sizes, int n_in,
                              void* d_out, int out_size, void* d_ws, size_t ws_size,
                              hipStream_t stream)
{
  const float* q  = (const float*)d_in[0];
  const float* k  = (const float*)d_in[1];
  const float* v  = (const float*)d_in[2];
  const int* mask = (const int*)d_in[3];

  float* out   = (float*)d_out;
  float* score = out + (long)BB * HH * SS * DD;   // +8388608

  const long sQK = (long)SS * DD;   // per (b,h) slice of q/k/v
  const long sSC = (long)SS * SS;   // per (b,h) plane of score

  // K1: score_pre = q @ k_reshaped(d,s) * (1/sqrt(D))
  // B-operand = k slice viewed as [D][S] row-major (reshape semantics) -> ldb=S
  gemm_bf16<<<dim3(SS / 128, SS / 128, BB * HH), 256, 0, stream>>>(
      q, k, score, DD,
      (long)DD, (long)SS, (long)SS,
      sQK, sQK, sSC, 0.08838834764831845f);

  // K2: in-place softmax over heads + mask
  softmax_heads<<<dim3((BB * SS * (SS / 4)) / 256), 256, 0, stream>>>(score, mask);

  // K3: out = score @ v
  gemm_bf16<<<dim3(SS / 128, DD / 128, BB * HH), 256, 0, stream>>>(
      score, v, out, SS,
      (long)SS, (long)DD, (long)DD,
      sSC, sQK, sQK, 1.0f);
}